// Round 1
// baseline (2051.540 us; speedup 1.0000x reference)
//
#include <hip/hip_runtime.h>

#define B 16
#define NN 200000
#define R 1000000
#define ITERS 5

__device__ __forceinline__ float sigmoidf_(float x) {
    return 1.0f / (1.0f + __expf(-x));
}

// Init: curr_logits (in d_out) = evidence; q_nb = sigmoid(evidence) in [N][B]; delta_nb = 0.
__global__ void cavi_init(const float* __restrict__ ev,
                          float* __restrict__ logits,
                          float* __restrict__ q_nb,
                          float* __restrict__ delta_nb) {
    int i = blockIdx.x * blockDim.x + threadIdx.x;   // over N*B, [n][b] layout
    if (i >= NN * B) return;
    int b = i & 15, n = i >> 4;
    float e = ev[b * NN + n];
    logits[b * NN + n] = e;
    q_nb[i] = sigmoidf_(e);
    delta_nb[i] = 0.0f;
}

// Edges: 1 thread per (edge, batch). Lanes 0..15 of each 16-lane group share an edge.
// q_nb/delta_nb in [N][B] layout -> 64B coalesced gathers and atomic bursts.
__global__ void cavi_edges(const float* __restrict__ q,
                           float* __restrict__ delta,
                           const int* __restrict__ idx1, const float* __restrict__ w1,
                           const int* __restrict__ idx2, const float* __restrict__ w2,
                           const int* __restrict__ idx3, const float* __restrict__ w3) {
    int gid = blockIdx.x * blockDim.x + threadIdx.x;   // < 3*R*16 = 48M, fits int
    int b = gid & 15;
    int e = gid >> 4;                                   // < 3*R
    if (e >= 3 * R) return;
    if (e < R) {
        int a = idx1[e * 2 + 0];
        int c = idx1[e * 2 + 1];
        float w = w1[e];
        float qa = q[a * B + b];
        float qc = q[c * B + b];
        atomicAdd(&delta[c * B + b], w * qa);
        atomicAdd(&delta[a * B + b], w * (qc - 1.0f));
    } else if (e < 2 * R) {
        int ei = e - R;
        int a  = idx2[ei * 3 + 0];
        int bb = idx2[ei * 3 + 1];
        int c  = idx2[ei * 3 + 2];
        float w = w2[ei];
        float qa = q[a * B + b];
        float qb = q[bb * B + b];
        float qc = q[c * B + b];
        atomicAdd(&delta[c * B + b],  w * qa * qb);
        atomicAdd(&delta[a * B + b],  w * qb * (qc - 1.0f));
        atomicAdd(&delta[bb * B + b], w * qa * (qc - 1.0f));
    } else {
        int ei = e - 2 * R;
        int a  = idx3[ei * 3 + 0];
        int bb = idx3[ei * 3 + 1];
        int c  = idx3[ei * 3 + 2];
        float w = w3[ei];
        float qa = q[a * B + b];
        float qb = q[bb * B + b];
        float qc = q[c * B + b];
        atomicAdd(&delta[c * B + b],  w * qa * (1.0f - qb));
        atomicAdd(&delta[a * B + b],  w * (1.0f - qb) * (qc - 1.0f));
        atomicAdd(&delta[bb * B + b], w * qa * (1.0f - qc));
    }
}

// Update: logits = 0.5*logits + 0.5*(evidence + delta); q = sigmoid(logits).
// On the last iteration write q (the output) into d_out instead of logits.
__global__ void cavi_update(const float* __restrict__ ev,
                            float* __restrict__ logits,
                            float* __restrict__ q_nb,
                            float* __restrict__ delta_nb,
                            int write_q) {
    int i = blockIdx.x * blockDim.x + threadIdx.x;   // over N*B, [n][b] layout
    if (i >= NN * B) return;
    int b = i & 15, n = i >> 4;
    float d = delta_nb[i];
    delta_nb[i] = 0.0f;                               // reset for next iteration
    float e  = ev[b * NN + n];
    float cl = logits[b * NN + n];
    float nl = 0.5f * cl + 0.5f * (e + d);
    float qv = sigmoidf_(nl);
    q_nb[i] = qv;
    logits[b * NN + n] = write_q ? qv : nl;
}

extern "C" void kernel_launch(void* const* d_in, const int* in_sizes, int n_in,
                              void* d_out, int out_size, void* d_ws, size_t ws_size,
                              hipStream_t stream) {
    const float* ev   = (const float*)d_in[0];
    const float* w1   = (const float*)d_in[1];
    const float* w2   = (const float*)d_in[2];
    const float* w3   = (const float*)d_in[3];
    const int*   idx1 = (const int*)d_in[4];
    const int*   idx2 = (const int*)d_in[5];
    const int*   idx3 = (const int*)d_in[6];

    float* logits   = (float*)d_out;                  // B*N floats, doubles as logits scratch
    float* q_nb     = (float*)d_ws;                   // N*B floats
    float* delta_nb = q_nb + (size_t)NN * B;          // N*B floats

    const int ethreads = 256;
    const int nb_total = NN * B;                      // 3.2M
    const int nb_grid  = (nb_total + ethreads - 1) / ethreads;
    const int edge_total = 3 * R * B;                 // 48M threads
    const int edge_grid  = (edge_total + ethreads - 1) / ethreads;

    cavi_init<<<nb_grid, ethreads, 0, stream>>>(ev, logits, q_nb, delta_nb);
    for (int it = 0; it < ITERS; ++it) {
        cavi_edges<<<edge_grid, ethreads, 0, stream>>>(q_nb, delta_nb,
                                                       idx1, w1, idx2, w2, idx3, w3);
        cavi_update<<<nb_grid, ethreads, 0, stream>>>(ev, logits, q_nb, delta_nb,
                                                      it == ITERS - 1 ? 1 : 0);
    }
}